// Round 7
// baseline (88.169 us; speedup 1.0000x reference)
//
#include <hip/hip_runtime.h>

#define TT 200
#define DD 64
#define BLOCK 256
#define KSH 68      // bf16 halfwords per K row (136 B rows)
#define NTILE 13    // ceil(200/16); last tile clamped to t0=184
#define BPB 4       // batches per block (pipelined)

typedef unsigned short u16;
typedef unsigned int u32;
typedef __attribute__((ext_vector_type(8))) u16 ushort8;
typedef __attribute__((ext_vector_type(8))) short short8v;  // MFMA bf16x8 frag
typedef __attribute__((ext_vector_type(4))) float f32x4;    // MFMA acc

union Frag { uint2 h[2]; short8v v; };

__device__ __forceinline__ float bflo(u32 w) {
    union { u32 u; float f; } v; v.u = w << 16; return v.f;
}
__device__ __forceinline__ float bfhi(u32 w) {
    union { u32 u; float f; } v; v.u = w & 0xFFFF0000u; return v.f;
}
__device__ __forceinline__ float bf2f(u16 h) {
    union { u32 u; float f; } v; v.u = ((u32)h) << 16; return v.f;
}
__device__ __forceinline__ u16 f2bf(float f) {
    union { float f; u32 u; } v; v.f = f;
    return (u16)((v.u + 0x7FFFu + ((v.u >> 16) & 1u)) >> 16);
}
__device__ __forceinline__ u32 cvt_pk_bf16(float lo, float hi) {
    u32 r;
    asm("v_cvt_pk_bf16_f32 %0, %1, %2" : "=v"(r) : "v"(lo), "v"(hi));
    return r;
}
__device__ __forceinline__ float sigmoid_fast(float x) {
    return __builtin_amdgcn_rcpf(1.0f + __expf(-x));
}

__global__ __launch_bounds__(BLOCK, 4) void attn_pool_kernel(
    const float* __restrict__ queries, const float* __restrict__ keys,
    const int* __restrict__ masks, const float* __restrict__ W1,
    const float* __restrict__ b1, const float* __restrict__ W2,
    const float* __restrict__ b2, const float* __restrict__ W3,
    const float* __restrict__ b3, float* __restrict__ out, int nB)
{
    __shared__ __align__(16) u16   lds_kh[TT][KSH];   // 27,200 B
    __shared__ __align__(16) u16   lds_cwt[16][KSH];  // 2,176 B; per-iter alias: e/part
    __shared__ __align__(16) u16   lds_s[TT][8];      // 3,200 B scores bf16
    __shared__ __align__(16) float lds_qw1[8];
    __shared__ __align__(16) float lds_w[49];         // 0..31 W2, 32..35 W3, 36..39 b2, 40 b3, 41..48 b1
    float* lds_e = (float*)&lds_cwt[0][0];                 // [200] f32
    float* part  = (float*)((char*)&lds_cwt[0][0] + 800);  // [4][64] f32

    const int tid = threadIdx.x;
    const int wave = tid >> 6;
    const int lane = tid & 63;
    const int b0 = blockIdx.x * BPB;

    // ---- batch-independent preloads (BEFORE any kraw issue: keeps vmcnt queue clean) ----
    const int d_f = tid & 63;
    const int j0 = tid >> 6;        // fold slot 1: row j0
    const int j1 = j0 + 4;          // fold slot 2: row j0+4
    const float wbc0 = W1[(64 + d_f) * 8 + j0] - W1[(128 + d_f) * 8 + j0];
    const float wd0  = W1[(192 + d_f) * 8 + j0];
    const float wbc1 = W1[(64 + d_f) * 8 + j1] - W1[(128 + d_f) * 8 + j1];
    const float wd1  = W1[(192 + d_f) * 8 + j1];
    float qa[8];                    // wave0: (W1a+W1c)[lane][0..7]
    if (wave == 0) {
        const float4* wa = (const float4*)&W1[lane * 8];
        const float4* wc = (const float4*)&W1[(128 + lane) * 8];
        float4 a0 = wa[0], a1 = wa[1], c0 = wc[0], c1 = wc[1];
        qa[0] = a0.x + c0.x; qa[1] = a0.y + c0.y; qa[2] = a0.z + c0.z; qa[3] = a0.w + c0.w;
        qa[4] = a1.x + c1.x; qa[5] = a1.y + c1.y; qa[6] = a1.z + c1.z; qa[7] = a1.w + c1.w;
    }
    if (tid < 32)                lds_w[tid] = W2[tid];
    else if (tid < 36)           lds_w[tid] = W3[tid - 32];
    else if (tid < 40)           lds_w[tid] = b2[tid - 36];
    else if (tid == 40)          lds_w[40]  = b3[0];
    else if (tid >= 41 && tid < 49) lds_w[tid] = b1[tid - 41];

    // ---- prologue: issue batch b0's keys + masks into regs ----
    int m0 = 0, m1 = 0;
    float4 kraw[14];
    {
        if (tid < 100) { m0 = masks[b0 * TT + tid]; m1 = masks[b0 * TT + tid + 100]; }
        const float4* kp = (const float4*)(keys + (size_t)b0 * TT * DD);
#pragma unroll
        for (int k = 0; k < 7; ++k) {
            int idx = tid + (k << 8);
            if (idx < 1600) { kraw[2 * k] = kp[2 * idx]; kraw[2 * k + 1] = kp[2 * idx + 1]; }
        }
    }

    for (int it = 0; it < BPB; ++it) {
        const int b = b0 + it;
        if (b >= nB) break;

        // ---- stage: kraw -> bf16 LDS (b128 writes); drains vmcnt progressively ----
#pragma unroll
        for (int k = 0; k < 7; ++k) {
            int idx = tid + (k << 8);
            if (idx < 1600) {
                float4 va = kraw[2 * k], vb = kraw[2 * k + 1];
                uint4 w;
                w.x = cvt_pk_bf16(va.x, va.y); w.y = cvt_pk_bf16(va.z, va.w);
                w.z = cvt_pk_bf16(vb.x, vb.y); w.w = cvt_pk_bf16(vb.z, vb.w);
                int row = idx >> 3, col = (idx & 7) << 3;
                *(uint4*)&lds_kh[row][col] = w;
            }
        }
        const int mm0 = m0, mm1 = m1;

        // ---- fold cwt for this batch (only q is a new global read) ----
        const float qd = queries[b * DD + d_f];
        lds_cwt[j0][d_f] = f2bf(fmaf(qd, wd0, wbc0));
        lds_cwt[j1][d_f] = f2bf(fmaf(qd, wd1, wbc1));

        // ---- qw1[j] = b1[j] + sum_d q[d]*(W1a+W1c)[d][j]  (wave 0) ----
        if (wave == 0) {
            float p8[8];
#pragma unroll
            for (int j = 0; j < 8; ++j) p8[j] = qd * qa[j];
#pragma unroll
            for (int j = 0; j < 8; ++j) {
#pragma unroll
                for (int off = 32; off; off >>= 1)
                    p8[j] += __shfl_xor(p8[j], off, 64);
            }
            if (lane == 0) {
#pragma unroll
                for (int j = 0; j < 8; ++j) lds_qw1[j] = p8[j] + lds_w[41 + j];
            }
        }
        __syncthreads();   // B1: kh, cwt, qw1 ready

        // ---- issue NEXT batch's loads (stream in under score+tail+PV) ----
        if (it + 1 < BPB && b + 1 < nB) {
            const int bn = b + 1;
            if (tid < 100) { m0 = masks[bn * TT + tid]; m1 = masks[bn * TT + tid + 100]; }
            const float4* kp = (const float4*)(keys + (size_t)bn * TT * DD);
#pragma unroll
            for (int k = 0; k < 7; ++k) {
                int idx = tid + (k << 8);
                if (idx < 1600) { kraw[2 * k] = kp[2 * idx]; kraw[2 * k + 1] = kp[2 * idx + 1]; }
            }
        }

        // ---- score GEMM via MFMA: S = K @ CW ----
        {
            const int r = lane & 15, g = lane >> 4;
            Frag bf0, bf1;
            bf0.h[0] = *(const uint2*)&lds_cwt[r][g * 8];
            bf0.h[1] = *(const uint2*)&lds_cwt[r][g * 8 + 4];
            bf1.h[0] = *(const uint2*)&lds_cwt[r][32 + g * 8];
            bf1.h[1] = *(const uint2*)&lds_cwt[r][32 + g * 8 + 4];
            for (int tile = wave; tile < NTILE; tile += 4) {
                int t0 = tile << 4;
                if (t0 > TT - 16) t0 = TT - 16;   // rows 184-191 dup-computed (identical)
                Frag a0, a1;
                a0.h[0] = *(const uint2*)&lds_kh[t0 + r][g * 8];
                a0.h[1] = *(const uint2*)&lds_kh[t0 + r][g * 8 + 4];
                a1.h[0] = *(const uint2*)&lds_kh[t0 + r][32 + g * 8];
                a1.h[1] = *(const uint2*)&lds_kh[t0 + r][32 + g * 8 + 4];
                f32x4 acc = {0.0f, 0.0f, 0.0f, 0.0f};
                acc = __builtin_amdgcn_mfma_f32_16x16x32_bf16(a0.v, bf0.v, acc, 0, 0, 0);
                acc = __builtin_amdgcn_mfma_f32_16x16x32_bf16(a1.v, bf1.v, acc, 0, 0, 0);
                if (r < 8) {                      // D: col(j)=lane&15, row(t)=g*4+reg
                    const int rr = t0 + (g << 2);
                    lds_s[rr + 0][r] = f2bf(acc[0]);
                    lds_s[rr + 1][r] = f2bf(acc[1]);
                    lds_s[rr + 2][r] = f2bf(acc[2]);
                    lds_s[rr + 3][r] = f2bf(acc[3]);
                }
            }
        }
        __syncthreads();   // B2: S ready; cwt dead

        // ---- MLP tail: threads 0..99, rows (t, t+100) ----
        if (tid < 100) {
            const int t0 = tid, t1 = tid + 100;
            ushort8 sa8 = *(const ushort8*)&lds_s[t0][0];
            ushort8 sb8 = *(const ushort8*)&lds_s[t1][0];
            float4 qwA = *(const float4*)&lds_qw1[0];
            float4 qwB = *(const float4*)&lds_qw1[4];
            float qw[8] = {qwA.x, qwA.y, qwA.z, qwA.w, qwB.x, qwB.y, qwB.z, qwB.w};
            float h1a[8], h1b[8];
#pragma unroll
            for (int j = 0; j < 8; ++j) {
                h1a[j] = sigmoid_fast(bf2f(sa8[j]) + qw[j]);
                h1b[j] = sigmoid_fast(bf2f(sb8[j]) + qw[j]);
            }
            float sa = lds_w[40], sb = lds_w[40];
#pragma unroll
            for (int c = 0; c < 4; ++c) {
                float ha = lds_w[36 + c], hb = ha;
#pragma unroll
                for (int j = 0; j < 8; ++j) {
                    float w2 = lds_w[j * 4 + c];
                    ha = fmaf(h1a[j], w2, ha);
                    hb = fmaf(h1b[j], w2, hb);
                }
                float w3 = lds_w[32 + c];
                sa = fmaf(sigmoid_fast(ha), w3, sa);
                sb = fmaf(sigmoid_fast(hb), w3, sb);
            }
            // no-max softmax: |score| bounded (<~0.5), masked -> exactly 0
            lds_e[t0] = mm0 ? __expf(sa) : 0.0f;
            lds_e[t1] = mm1 ? __expf(sb) : 0.0f;
        }
        __syncthreads();   // B3: e ready

        // ---- PV from bf16 LDS (0-conflict): lane = (half, d-pair) ----
        const int half = lane >> 5;
        const int dp = lane & 31;
        const int d0 = dp << 1;
        const int tbase = (wave << 1) + half;   // 0..7
        float acc0 = 0.0f, acc1 = 0.0f;
#pragma unroll
        for (int i = 0; i < 25; ++i) {
            const int t = tbase + (i << 3);
            u32 kw = *(const u32*)&lds_kh[t][d0];
            float e = lds_e[t];
            acc0 = fmaf(e, bflo(kw), acc0);
            acc1 = fmaf(e, bfhi(kw), acc1);
        }
        acc0 += __shfl_xor(acc0, 32, 64);
        acc1 += __shfl_xor(acc1, 32, 64);
        if (half == 0) {
            float2 wpack; wpack.x = acc0; wpack.y = acc1;
            *(float2*)&part[wave * DD + d0] = wpack;
        }
        __syncthreads();   // B4: partials ready

        // ---- epilogue (wave 0): e-sum + combine + store ----
        if (wave == 0) {
            float s = lds_e[lane] + lds_e[64 + lane] + lds_e[128 + lane];
            if (lane < 8) s += lds_e[192 + lane];
#pragma unroll
            for (int off = 32; off; off >>= 1) s += __shfl_xor(s, off, 64);
            float r = part[lane] + part[DD + lane] + part[2 * DD + lane] + part[3 * DD + lane];
            out[b * DD + lane] = r / s;
        }
        __syncthreads();   // B5: protect kh/cwt aliases for next iteration
    }
}

extern "C" void kernel_launch(void* const* d_in, const int* in_sizes, int n_in,
                              void* d_out, int out_size, void* d_ws, size_t ws_size,
                              hipStream_t stream) {
    const float* queries = (const float*)d_in[0];
    const float* keys    = (const float*)d_in[1];
    const int*   masks   = (const int*)d_in[2];
    const float* W1      = (const float*)d_in[3];
    const float* b1      = (const float*)d_in[4];
    const float* W2      = (const float*)d_in[5];
    const float* b2      = (const float*)d_in[6];
    const float* W3      = (const float*)d_in[7];
    const float* b3      = (const float*)d_in[8];
    float* out = (float*)d_out;

    const int B = in_sizes[0] / DD;                 // 4096
    const int nblocks = (B + BPB - 1) / BPB;        // 1024
    attn_pool_kernel<<<nblocks, BLOCK, 0, stream>>>(queries, keys, masks, W1, b1, W2, b2, W3, b3, out, B);
}

// Round 8
// 78.282 us; speedup vs baseline: 1.1263x; 1.1263x over previous
//
#include <hip/hip_runtime.h>

#define TT 200
#define DD 64
#define BLOCK 256
#define KSH 72      // bf16 halfs per kh row (144 B = 9 granules -> 2-way-free frag reads)
#define CWS 136     // bf16 halfs per cwt row (272 B = 17 granules, odd -> conflict-free)
#define NTILE 13    // ceil(200/16); last tile clamped to t0=184 (rows 184-191 dup, identical)
#define BPB 4       // batches per persistent block

typedef unsigned short u16;
typedef unsigned int u32;
typedef __attribute__((ext_vector_type(8))) short short8v;  // MFMA bf16x8 frag
typedef __attribute__((ext_vector_type(4))) float f32x4;    // MFMA acc

union Frag { uint4 q; short8v v; };

__device__ __forceinline__ float bflo(u32 w) {
    union { u32 u; float f; } v; v.u = w << 16; return v.f;
}
__device__ __forceinline__ float bfhi(u32 w) {
    union { u32 u; float f; } v; v.u = w & 0xFFFF0000u; return v.f;
}
__device__ __forceinline__ u16 f2bf(float f) {
    union { float f; u32 u; } v; v.f = f;
    return (u16)((v.u + 0x7FFFu + ((v.u >> 16) & 1u)) >> 16);
}
__device__ __forceinline__ u32 cvt_pk_bf16(float lo, float hi) {
    u32 r;
    asm("v_cvt_pk_bf16_f32 %0, %1, %2" : "=v"(r) : "v"(lo), "v"(hi));
    return r;
}
__device__ __forceinline__ float sigmoid_fast(float x) {
    return __builtin_amdgcn_rcpf(1.0f + __expf(-x));
}

// LDS-only barrier: drain this wave's LDS ops, sync, fence the scheduler.
// Deliberately NO vmcnt drain: prefetch global loads stay in flight (T4).
#define BARRIER() do {                                              \
    asm volatile("s_waitcnt lgkmcnt(0)" ::: "memory");              \
    __builtin_amdgcn_sched_barrier(0);                              \
    __builtin_amdgcn_s_barrier();                                   \
    __builtin_amdgcn_sched_barrier(0);                              \
} while (0)

__global__ __launch_bounds__(BLOCK, 4) void attn_pool_kernel(
    const float* __restrict__ queries, const float* __restrict__ keys,
    const int* __restrict__ masks, const float* __restrict__ W1,
    const float* __restrict__ b1, const float* __restrict__ W2,
    const float* __restrict__ b2, const float* __restrict__ W3,
    const float* __restrict__ b3, float* __restrict__ out, int nB)
{
    __shared__ __align__(16) u16   lds_kh[TT][KSH];    // 28,800 B
    __shared__ __align__(16) u16   lds_cwt[16][CWS];   // 4,352 B  cols 0..63 CW (per batch), 64..127 AC (constant)
    __shared__ __align__(16) u16   lds_q16[DD];        // 128 B    q bf16 (per batch)
    __shared__ __align__(16) float lds_s[TT][8];       // 6,400 B  scores fp32
    __shared__ __align__(16) float lds_w[49];          // 196 B    0..31 W2, 32..35 W3, 36..39 b2, 40..47 b1, 48 b3
    __shared__ __align__(16) float lds_e[TT];          // 800 B    => 40,676 B total -> 4 blocks/CU
    float* part = (float*)&lds_s[100][0];              // [4][64] f32 alias (lds_s dead after tail)

    const int tid = threadIdx.x;
    const int wave = tid >> 6;
    const int lane = tid & 63;
    const int b0 = blockIdx.x * BPB;

    // ================= prologue: ALL batch-scalar global reads first =================
    const int d_f = tid & 63;
    const int jr = tid >> 6;            // 0..3 ; this thread folds rows (jr, jr+4) at col d_f
    const float wbc0 = W1[(64 + d_f) * 8 + jr]     - W1[(128 + d_f) * 8 + jr];
    const float wd0  = W1[(192 + d_f) * 8 + jr];
    const float wac0 = W1[d_f * 8 + jr]            + W1[(128 + d_f) * 8 + jr];
    const float wbc1 = W1[(64 + d_f) * 8 + jr + 4] - W1[(128 + d_f) * 8 + jr + 4];
    const float wd1  = W1[(192 + d_f) * 8 + jr + 4];
    const float wac1 = W1[d_f * 8 + jr + 4]        + W1[(128 + d_f) * 8 + jr + 4];
    if (tid < 32)                    lds_w[tid] = W2[tid];
    else if (tid < 36)               lds_w[tid] = W3[tid - 32];
    else if (tid < 40)               lds_w[tid] = b2[tid - 36];
    else if (tid < 48)               lds_w[tid] = b1[tid - 40];
    else if (tid == 48)              lds_w[48]  = b3[0];
    // AC part of cwt is batch-independent: write once
    lds_cwt[jr][64 + d_f]     = f2bf(wac0);
    lds_cwt[jr + 4][64 + d_f] = f2bf(wac1);

    // q and masks for all BPB batches (hoisted so nothing later disturbs the kraw FIFO)
    float qv[BPB];
    int mA[BPB], mB[BPB];
#pragma unroll
    for (int i = 0; i < BPB; ++i) {
        int bb = b0 + i; if (bb > nB - 1) bb = nB - 1;
        qv[i] = queries[(size_t)bb * DD + d_f];
        if (tid < 100) {
            mA[i] = masks[(size_t)bb * TT + tid];
            mB[i] = masks[(size_t)bb * TT + tid + 100];
        } else { mA[i] = 0; mB[i] = 0; }
    }

    // issue batch b0's key loads (pairs of float4 -> 8 floats per idx)
    float4 kraw[14];
    {
        const float4* kp = (const float4*)(keys + (size_t)b0 * TT * DD);
#pragma unroll
        for (int k = 0; k < 7; ++k) {
            int idx = tid + (k << 8);
            if (idx < 1600) { kraw[2 * k] = kp[2 * idx]; kraw[2 * k + 1] = kp[2 * idx + 1]; }
        }
    }
    __builtin_amdgcn_sched_barrier(0);

#pragma unroll
    for (int it = 0; it < BPB; ++it) {
        const int b = b0 + it;
        if (b >= nB) break;

        // ---- STAGE: kraw -> bf16 kh (b128 writes); vmcnt drains progressively ----
#pragma unroll
        for (int k = 0; k < 7; ++k) {
            int idx = tid + (k << 8);
            if (idx < 1600) {
                float4 va = kraw[2 * k], vb = kraw[2 * k + 1];
                uint4 w;
                w.x = cvt_pk_bf16(va.x, va.y); w.y = cvt_pk_bf16(va.z, va.w);
                w.z = cvt_pk_bf16(vb.x, vb.y); w.w = cvt_pk_bf16(vb.z, vb.w);
                int row = idx >> 3, col = (idx & 7) << 3;
                *(uint4*)&lds_kh[row][col] = w;
            }
        }
        // ---- PREFETCH next batch's keys; pin issue point ----
        if (it + 1 < BPB && b + 1 < nB) {
            const float4* kp = (const float4*)(keys + (size_t)(b + 1) * TT * DD);
#pragma unroll
            for (int k = 0; k < 7; ++k) {
                int idx = tid + (k << 8);
                if (idx < 1600) { kraw[2 * k] = kp[2 * idx]; kraw[2 * k + 1] = kp[2 * idx + 1]; }
            }
        }
        __builtin_amdgcn_sched_barrier(0);

        // ---- fold per-batch cwt cols 0..63 and q16 (VALU + tiny LDS writes) ----
        lds_cwt[jr][d_f]     = f2bf(fmaf(qv[it], wd0, wbc0));
        lds_cwt[jr + 4][d_f] = f2bf(fmaf(qv[it], wd1, wbc1));
        if (tid < DD) lds_q16[tid] = f2bf(qv[it]);
        BARRIER();   // B1: kh, cwt, q16 ready (kraw prefetch still in flight)

        // ---- score GEMM (K=128): S = [K | q] @ [CW ; AC]  -> lds_s fp32 ----
        {
            const int r = lane & 15, g = lane >> 4;
            Frag bf0, bf1, bq0, bq1, aq0, aq1;
            bf0.q = *(const uint4*)&lds_cwt[r][g * 8];
            bf1.q = *(const uint4*)&lds_cwt[r][32 + g * 8];
            bq0.q = *(const uint4*)&lds_cwt[r][64 + g * 8];
            bq1.q = *(const uint4*)&lds_cwt[r][96 + g * 8];
            aq0.q = *(const uint4*)&lds_q16[g * 8];        // row-constant A (q)
            aq1.q = *(const uint4*)&lds_q16[32 + g * 8];
            f32x4 zero = {0.0f, 0.0f, 0.0f, 0.0f};
            f32x4 acc_base = __builtin_amdgcn_mfma_f32_16x16x32_bf16(aq1.v, bq1.v, zero, 0, 0, 0);
            acc_base = __builtin_amdgcn_mfma_f32_16x16x32_bf16(aq0.v, bq0.v, acc_base, 0, 0, 0);
            for (int tile = wave; tile < NTILE; tile += 4) {
                int t0 = tile << 4;
                if (t0 > TT - 16) t0 = TT - 16;
                Frag a0, a1;
                a0.q = *(const uint4*)&lds_kh[t0 + r][g * 8];
                a1.q = *(const uint4*)&lds_kh[t0 + r][32 + g * 8];
                f32x4 acc = __builtin_amdgcn_mfma_f32_16x16x32_bf16(a0.v, bf0.v, acc_base, 0, 0, 0);
                acc = __builtin_amdgcn_mfma_f32_16x16x32_bf16(a1.v, bf1.v, acc, 0, 0, 0);
                if (r < 8) {                 // D: col(j)=lane&15, row(t)=g*4+reg
                    const int rr = t0 + (g << 2);
                    lds_s[rr + 0][r] = acc[0];
                    lds_s[rr + 1][r] = acc[1];
                    lds_s[rr + 2][r] = acc[2];
                    lds_s[rr + 3][r] = acc[3];
                }
            }
        }
        BARRIER();   // B2: S ready

        // ---- MLP tail: threads 0..99, rows (t, t+100) ----
        if (tid < 100) {
            const int t0 = tid, t1 = tid + 100;
            float4 sa0 = *(const float4*)&lds_s[t0][0];
            float4 sa1 = *(const float4*)&lds_s[t0][4];
            float4 sb0 = *(const float4*)&lds_s[t1][0];
            float4 sb1 = *(const float4*)&lds_s[t1][4];
            float4 b1A = *(const float4*)&lds_w[40];
            float4 b1B = *(const float4*)&lds_w[44];
            float h1a[8], h1b[8];
            h1a[0] = sigmoid_fast(sa0.x + b1A.x); h1b[0] = sigmoid_fast(sb0.x + b1A.x);
            h1a[1] = sigmoid_fast(sa0.y + b1A.y); h1b[1] = sigmoid_fast(sb0.y + b1A.y);
            h1a[2] = sigmoid_fast(sa0.z + b1A.z); h1b[2] = sigmoid_fast(sb0.z + b1A.z);
            h1a[3] = sigmoid_fast(sa0.w + b1A.w); h1b[3] = sigmoid_fast(sb0.w + b1A.w);
            h1a[4] = sigmoid_fast(sa1.x + b1B.x); h1b[4] = sigmoid_fast(sb1.x + b1B.x);
            h1a[5] = sigmoid_fast(sa1.y + b1B.y); h1b[5] = sigmoid_fast(sb1.y + b1B.y);
            h1a[6] = sigmoid_fast(sa1.z + b1B.z); h1b[6] = sigmoid_fast(sb1.z + b1B.z);
            h1a[7] = sigmoid_fast(sa1.w + b1B.w); h1b[7] = sigmoid_fast(sb1.w + b1B.w);
            float sa = lds_w[48], sb = lds_w[48];
#pragma unroll
            for (int c = 0; c < 4; ++c) {
                float ha = lds_w[36 + c], hb = ha;
#pragma unroll
                for (int j = 0; j < 8; ++j) {
                    float w2 = lds_w[j * 4 + c];
                    ha = fmaf(h1a[j], w2, ha);
                    hb = fmaf(h1b[j], w2, hb);
                }
                float w3 = lds_w[32 + c];
                sa = fmaf(sigmoid_fast(ha), w3, sa);
                sb = fmaf(sigmoid_fast(hb), w3, sb);
            }
            // no-max softmax: |score| bounded (<~0.5), masked -> exactly 0
            lds_e[t0] = mA[it] ? __expf(sa) : 0.0f;
            lds_e[t1] = mB[it] ? __expf(sb) : 0.0f;
        }
        BARRIER();   // B3: e ready; lds_s dead -> part alias live

        // ---- PV from bf16 kh (0-conflict): lane = (half, d-pair) ----
        {
            const int half = lane >> 5;
            const int dp = lane & 31;
            const int d0 = dp << 1;
            const int tbase = (wave << 1) + half;   // 0..7
            float acc0 = 0.0f, acc1 = 0.0f;
#pragma unroll
            for (int i = 0; i < 25; ++i) {
                const int t = tbase + (i << 3);
                u32 kw = *(const u32*)&lds_kh[t][d0];
                float e = lds_e[t];
                acc0 = fmaf(e, bflo(kw), acc0);
                acc1 = fmaf(e, bfhi(kw), acc1);
            }
            acc0 += __shfl_xor(acc0, 32, 64);
            acc1 += __shfl_xor(acc1, 32, 64);
            if (half == 0) {
                float2 wpack; wpack.x = acc0; wpack.y = acc1;
                *(float2*)&part[wave * DD + d0] = wpack;
            }
        }
        BARRIER();   // B4: partials ready

        // ---- epilogue (wave 0): e-sum + combine + store ----
        if (wave == 0) {
            float s = lds_e[lane] + lds_e[64 + lane] + lds_e[128 + lane];
            if (lane < 8) s += lds_e[192 + lane];
#pragma unroll
            for (int off = 32; off; off >>= 1) s += __shfl_xor(s, off, 64);
            float r = part[lane] + part[DD + lane] + part[2 * DD + lane] + part[3 * DD + lane];
            out[(size_t)b * DD + lane] = r / s;
        }
        BARRIER();   // B5: protect kh/e/part/s for next iteration
    }
}

extern "C" void kernel_launch(void* const* d_in, const int* in_sizes, int n_in,
                              void* d_out, int out_size, void* d_ws, size_t ws_size,
                              hipStream_t stream) {
    const float* queries = (const float*)d_in[0];
    const float* keys    = (const float*)d_in[1];
    const int*   masks   = (const int*)d_in[2];
    const float* W1      = (const float*)d_in[3];
    const float* b1      = (const float*)d_in[4];
    const float* W2      = (const float*)d_in[5];
    const float* b2      = (const float*)d_in[6];
    const float* W3      = (const float*)d_in[7];
    const float* b3      = (const float*)d_in[8];
    float* out = (float*)d_out;

    const int B = in_sizes[0] / DD;                 // 4096
    const int nblocks = (B + BPB - 1) / BPB;        // 1024 persistent blocks = 4/CU
    attn_pool_kernel<<<nblocks, BLOCK, 0, stream>>>(queries, keys, masks, W1, b1, W2, b2, W3, b3, out, B);
}

// Round 9
// 62.642 us; speedup vs baseline: 1.4075x; 1.2497x over previous
//
#include <hip/hip_runtime.h>

#define TT 200
#define DD 64
#define BLOCK 256
#define KSH 68      // bf16 halfs per kh row: word-stride 34 = 2 mod 32 -> 2-way-free frag reads
#define CWS 132     // bf16 halfs per cwt row: word-stride 66 = 2 mod 32 -> 2-way-free
#define NTILE 13    // ceil(200/16); last tile clamped to t0=184 (rows 184-191 dup, identical)
#define BPB 4       // batches per persistent block; grid = B/BPB = 1024 = 4/CU resident

typedef unsigned short u16;
typedef unsigned int u32;
typedef __attribute__((ext_vector_type(8))) short short8v;  // MFMA bf16x8 frag
typedef __attribute__((ext_vector_type(4))) float f32x4;    // MFMA acc

union Frag { uint4 q; short8v v; };

__device__ __forceinline__ float bflo(u32 w) {
    union { u32 u; float f; } v; v.u = w << 16; return v.f;
}
__device__ __forceinline__ float bfhi(u32 w) {
    union { u32 u; float f; } v; v.u = w & 0xFFFF0000u; return v.f;
}
__device__ __forceinline__ u16 f2bf(float f) {
    union { float f; u32 u; } v; v.f = f;
    return (u16)((v.u + 0x7FFFu + ((v.u >> 16) & 1u)) >> 16);
}
__device__ __forceinline__ u32 cvt_pk_bf16(float lo, float hi) {
    u32 r;
    asm("v_cvt_pk_bf16_f32 %0, %1, %2" : "=v"(r) : "v"(lo), "v"(hi));
    return r;
}
__device__ __forceinline__ float sigmoid_fast(float x) {
    return __builtin_amdgcn_rcpf(1.0f + __expf(-x));
}

// LDS-only barrier: drain LDS ops, sync, fence scheduler. NO vmcnt drain:
// prefetch global loads stay in flight across it (T4 principle).
#define BARRIER() do {                                              \
    asm volatile("s_waitcnt lgkmcnt(0)" ::: "memory");              \
    __builtin_amdgcn_sched_barrier(0);                              \
    __builtin_amdgcn_s_barrier();                                   \
    __builtin_amdgcn_sched_barrier(0);                              \
} while (0)

__global__ __launch_bounds__(BLOCK)
__attribute__((amdgpu_waves_per_eu(4, 4)))   // pin 4 waves/EU -> 128-VGPR budget (stop the 64-reg spill)
void attn_pool_kernel(
    const float* __restrict__ queries, const float* __restrict__ keys,
    const int* __restrict__ masks, const float* __restrict__ W1,
    const float* __restrict__ b1, const float* __restrict__ W2,
    const float* __restrict__ b2, const float* __restrict__ W3,
    const float* __restrict__ b3, float* __restrict__ out, int nB)
{
    __shared__ __align__(16) u16   lds_kh[TT][KSH];    // 27,200 B
    __shared__ __align__(16) u16   lds_cwt[16][CWS];   // 4,224 B  cols 0..63 CW (per batch), 64..127 AC (const)
    __shared__ __align__(16) u16   lds_q16[DD];        // 128 B
    __shared__ __align__(16) float lds_s[TT][8];       // 6,400 B  scores fp32
    __shared__ __align__(16) float lds_w[52];          // 208 B    0..31 W2, 32..35 W3, 36..39 b2, 40..47 b1, 48 b3
    __shared__ __align__(16) float lds_e[TT];          // 800 B    => 38,960 B -> 4 blocks/CU
    float* part = (float*)&lds_s[100][0];              // [4][64] f32 alias (s[100..] dead when part live)

    const int tid = threadIdx.x;
    const int wave = tid >> 6;
    const int lane = tid & 63;
    const int b0 = blockIdx.x * BPB;

    // ================= prologue: ALL batch-scalar global reads first =================
    const int d_f = tid & 63;
    const int jr = tid >> 6;            // this thread folds rows (jr, jr+4) at col d_f
    const float w1c0 = W1[(128 + d_f) * 8 + jr];
    const float wbc0 = W1[(64 + d_f) * 8 + jr] - w1c0;
    const float wd0  = W1[(192 + d_f) * 8 + jr];
    const float wac0 = W1[d_f * 8 + jr] + w1c0;
    const float w1c1 = W1[(128 + d_f) * 8 + jr + 4];
    const float wbc1 = W1[(64 + d_f) * 8 + jr + 4] - w1c1;
    const float wd1  = W1[(192 + d_f) * 8 + jr + 4];
    const float wac1 = W1[d_f * 8 + jr + 4] + w1c1;
    if (tid < 32)                    lds_w[tid] = W2[tid];
    else if (tid < 36)               lds_w[tid] = W3[tid - 32];
    else if (tid < 40)               lds_w[tid] = b2[tid - 36];
    else if (tid < 48)               lds_w[tid] = b1[tid - 40];
    else if (tid == 48)              lds_w[48]  = b3[0];
    // AC half of cwt is batch-independent: write once
    lds_cwt[jr][64 + d_f]     = f2bf(wac0);
    lds_cwt[jr + 4][64 + d_f] = f2bf(wac1);

    // q and masks for all BPB batches (hoisted: nothing later disturbs the kraw FIFO)
    float qv[BPB];
    int mA[BPB], mB[BPB];
#pragma unroll
    for (int i = 0; i < BPB; ++i) {
        int bb = b0 + i; if (bb > nB - 1) bb = nB - 1;
        qv[i] = queries[(size_t)bb * DD + d_f];
        if (tid < 100) {
            mA[i] = masks[(size_t)bb * TT + tid];
            mB[i] = masks[(size_t)bb * TT + tid + 100];
        } else { mA[i] = 0; mB[i] = 0; }
    }

    // issue batch b0's key loads: 7 chunk-pairs, indices CLAMPED (no divergent defs)
    float4 kraw[14];
    {
        const float4* kp = (const float4*)(keys + (size_t)b0 * TT * DD);
#pragma unroll
        for (int k = 0; k < 7; ++k) {
            int idx = tid + (k << 8); idx = idx < 1600 ? idx : 1599;
            kraw[2 * k] = kp[2 * idx]; kraw[2 * k + 1] = kp[2 * idx + 1];
        }
    }
    __builtin_amdgcn_sched_barrier(0);

#pragma unroll
    for (int it = 0; it < BPB; ++it) {
        const int bcl = (b0 + it > nB - 1) ? (nB - 1) : (b0 + it);

        // ---- STAGE: kraw -> bf16 kh (b128 writes); waits drain kraw progressively ----
#pragma unroll
        for (int k = 0; k < 7; ++k) {
            int idx = tid + (k << 8);
            if (idx < 1600) {
                float4 va = kraw[2 * k], vb = kraw[2 * k + 1];
                uint4 w;
                w.x = cvt_pk_bf16(va.x, va.y); w.y = cvt_pk_bf16(va.z, va.w);
                w.z = cvt_pk_bf16(vb.x, vb.y); w.w = cvt_pk_bf16(vb.z, vb.w);
                int row = idx >> 3, col = (idx & 7) << 3;
                *(uint4*)&lds_kh[row][col] = w;
            }
        }
        // ---- PREFETCH next batch's keys (compile-time guard only) ----
        if (it + 1 < BPB) {
            int bn = b0 + it + 1; bn = bn > nB - 1 ? nB - 1 : bn;
            const float4* kp = (const float4*)(keys + (size_t)bn * TT * DD);
#pragma unroll
            for (int k = 0; k < 7; ++k) {
                int idx = tid + (k << 8); idx = idx < 1600 ? idx : 1599;
                kraw[2 * k] = kp[2 * idx]; kraw[2 * k + 1] = kp[2 * idx + 1];
            }
        }
        __builtin_amdgcn_sched_barrier(0);

        // ---- fold per-batch cwt cols 0..63 + q16 (VALU + tiny LDS writes) ----
        lds_cwt[jr][d_f]     = f2bf(fmaf(qv[it], wd0, wbc0));
        lds_cwt[jr + 4][d_f] = f2bf(fmaf(qv[it], wd1, wbc1));
        if (tid < DD) lds_q16[tid] = f2bf(qv[it]);
        BARRIER();   // B1: kh, cwt, q16 ready (prefetch still in flight)

        // ---- score GEMM (K=128): S = [K | q] @ [CW ; AC] -> lds_s fp32 ----
        {
            const int r = lane & 15, g = lane >> 4;
            Frag bf0, bf1, bq0, bq1, aq0, aq1;
            bf0.q = *(const uint4*)&lds_cwt[r][g * 8];
            bf1.q = *(const uint4*)&lds_cwt[r][32 + g * 8];
            bq0.q = *(const uint4*)&lds_cwt[r][64 + g * 8];
            bq1.q = *(const uint4*)&lds_cwt[r][96 + g * 8];
            aq0.q = *(const uint4*)&lds_q16[g * 8];        // row-constant A (q)
            aq1.q = *(const uint4*)&lds_q16[32 + g * 8];
            f32x4 zero = {0.0f, 0.0f, 0.0f, 0.0f};
            f32x4 acc_base = __builtin_amdgcn_mfma_f32_16x16x32_bf16(aq1.v, bq1.v, zero, 0, 0, 0);
            acc_base = __builtin_amdgcn_mfma_f32_16x16x32_bf16(aq0.v, bq0.v, acc_base, 0, 0, 0);
            for (int tile = wave; tile < NTILE; tile += 4) {
                int t0 = tile << 4;
                if (t0 > TT - 16) t0 = TT - 16;
                Frag a0, a1;
                a0.q = *(const uint4*)&lds_kh[t0 + r][g * 8];
                a1.q = *(const uint4*)&lds_kh[t0 + r][32 + g * 8];
                f32x4 acc = __builtin_amdgcn_mfma_f32_16x16x32_bf16(a0.v, bf0.v, acc_base, 0, 0, 0);
                acc = __builtin_amdgcn_mfma_f32_16x16x32_bf16(a1.v, bf1.v, acc, 0, 0, 0);
                if (r < 8) {                 // D: col(j)=lane&15, row(t)=g*4+reg
                    const int rr = t0 + (g << 2);
                    lds_s[rr + 0][r] = acc[0];
                    lds_s[rr + 1][r] = acc[1];
                    lds_s[rr + 2][r] = acc[2];
                    lds_s[rr + 3][r] = acc[3];
                }
            }
        }
        BARRIER();   // B2: S ready

        // ---- MLP tail: threads 0..99, rows (t, t+100) ----
        if (tid < 100) {
            const int t0 = tid, t1 = tid + 100;
            float4 sa0 = *(const float4*)&lds_s[t0][0];
            float4 sa1 = *(const float4*)&lds_s[t0][4];
            float4 sb0 = *(const float4*)&lds_s[t1][0];
            float4 sb1 = *(const float4*)&lds_s[t1][4];
            float4 b1A = *(const float4*)&lds_w[40];
            float4 b1B = *(const float4*)&lds_w[44];
            float h1a[8], h1b[8];
            h1a[0] = sigmoid_fast(sa0.x + b1A.x); h1b[0] = sigmoid_fast(sb0.x + b1A.x);
            h1a[1] = sigmoid_fast(sa0.y + b1A.y); h1b[1] = sigmoid_fast(sb0.y + b1A.y);
            h1a[2] = sigmoid_fast(sa0.z + b1A.z); h1b[2] = sigmoid_fast(sb0.z + b1A.z);
            h1a[3] = sigmoid_fast(sa0.w + b1A.w); h1b[3] = sigmoid_fast(sb0.w + b1A.w);
            h1a[4] = sigmoid_fast(sa1.x + b1B.x); h1b[4] = sigmoid_fast(sb1.x + b1B.x);
            h1a[5] = sigmoid_fast(sa1.y + b1B.y); h1b[5] = sigmoid_fast(sb1.y + b1B.y);
            h1a[6] = sigmoid_fast(sa1.z + b1B.z); h1b[6] = sigmoid_fast(sb1.z + b1B.z);
            h1a[7] = sigmoid_fast(sa1.w + b1B.w); h1b[7] = sigmoid_fast(sb1.w + b1B.w);
            float sa = lds_w[48], sb = lds_w[48];
#pragma unroll
            for (int c = 0; c < 4; ++c) {
                float ha = lds_w[36 + c], hb = ha;
#pragma unroll
                for (int j = 0; j < 8; ++j) {
                    float w2 = lds_w[j * 4 + c];
                    ha = fmaf(h1a[j], w2, ha);
                    hb = fmaf(h1b[j], w2, hb);
                }
                float w3 = lds_w[32 + c];
                sa = fmaf(sigmoid_fast(ha), w3, sa);
                sb = fmaf(sigmoid_fast(hb), w3, sb);
            }
            // no-max softmax: |score| bounded (<~0.5), masked -> exactly 0
            lds_e[t0] = mA[it] ? __expf(sa) : 0.0f;
            lds_e[t1] = mB[it] ? __expf(sb) : 0.0f;
        }
        BARRIER();   // B3: e ready; s[100..] dead -> part alias live

        // ---- PV from bf16 kh (2-way-free): lane = (half, d-pair) ----
        {
            const int half = lane >> 5;
            const int dp = lane & 31;
            const int d0 = dp << 1;
            const int tbase = (wave << 1) + half;   // 0..7
            float acc0 = 0.0f, acc1 = 0.0f;
#pragma unroll
            for (int i = 0; i < 25; ++i) {
                const int t = tbase + (i << 3);
                u32 kw = *(const u32*)&lds_kh[t][d0];
                float e = lds_e[t];
                acc0 = fmaf(e, bflo(kw), acc0);
                acc1 = fmaf(e, bfhi(kw), acc1);
            }
            acc0 += __shfl_xor(acc0, 32, 64);
            acc1 += __shfl_xor(acc1, 32, 64);
            if (half == 0) {
                float2 wpack; wpack.x = acc0; wpack.y = acc1;
                *(float2*)&part[wave * DD + d0] = wpack;
            }
        }
        BARRIER();   // B4: partials ready

        // ---- epilogue (wave 0): e-sum + combine + store ----
        if (wave == 0) {
            float s = lds_e[lane] + lds_e[64 + lane] + lds_e[128 + lane];
            if (lane < 8) s += lds_e[192 + lane];
#pragma unroll
            for (int off = 32; off; off >>= 1) s += __shfl_xor(s, off, 64);
            float r = part[lane] + part[DD + lane] + part[2 * DD + lane] + part[3 * DD + lane];
            out[(size_t)bcl * DD + lane] = r / s;
        }
        BARRIER();   // B5: protect kh/e/part for next iteration
    }
}

extern "C" void kernel_launch(void* const* d_in, const int* in_sizes, int n_in,
                              void* d_out, int out_size, void* d_ws, size_t ws_size,
                              hipStream_t stream) {
    const float* queries = (const float*)d_in[0];
    const float* keys    = (const float*)d_in[1];
    const int*   masks   = (const int*)d_in[2];
    const float* W1      = (const float*)d_in[3];
    const float* b1      = (const float*)d_in[4];
    const float* W2      = (const float*)d_in[5];
    const float* b2      = (const float*)d_in[6];
    const float* W3      = (const float*)d_in[7];
    const float* b3      = (const float*)d_in[8];
    float* out = (float*)d_out;

    const int B = in_sizes[0] / DD;                 // 4096
    const int nblocks = (B + BPB - 1) / BPB;        // 1024 persistent blocks = 4/CU
    attn_pool_kernel<<<nblocks, BLOCK, 0, stream>>>(queries, keys, masks, W1, b1, W2, b2, W3, b3, out, B);
}

// Round 10
// 55.669 us; speedup vs baseline: 1.5838x; 1.1253x over previous
//
#include <hip/hip_runtime.h>

#define TT 200
#define DD 64
#define BLOCK 256
#define KSH 68      // bf16 halfs per kh row: word-stride 34 = 2 mod 32 -> 2-way-free frag reads
#define CWS 132     // bf16 halfs per cwt row: word-stride 66 = 2 mod 32 -> 2-way-free
#define NTILE 13    // ceil(200/16); last tile clamped to t0=184 (rows 184-191 dup-computed, identical)

typedef unsigned short u16;
typedef unsigned int u32;
typedef __attribute__((ext_vector_type(8))) u16 ushort8;
typedef __attribute__((ext_vector_type(8))) short short8v;  // MFMA bf16x8 frag
typedef __attribute__((ext_vector_type(4))) float f32x4;    // MFMA acc

union Frag { uint2 h[2]; short8v v; };

__device__ __forceinline__ float bflo(u32 w) {
    union { u32 u; float f; } v; v.u = w << 16; return v.f;
}
__device__ __forceinline__ float bfhi(u32 w) {
    union { u32 u; float f; } v; v.u = w & 0xFFFF0000u; return v.f;
}
__device__ __forceinline__ float bf2f(u16 h) {
    union { u32 u; float f; } v; v.u = ((u32)h) << 16; return v.f;
}
__device__ __forceinline__ u16 f2bf(float f) {
    union { float f; u32 u; } v; v.f = f;
    return (u16)((v.u + 0x7FFFu + ((v.u >> 16) & 1u)) >> 16);
}
__device__ __forceinline__ u32 cvt_pk_bf16(float lo, float hi) {
    u32 r;
    asm("v_cvt_pk_bf16_f32 %0, %1, %2" : "=v"(r) : "v"(lo), "v"(hi));
    return r;
}
__device__ __forceinline__ float sigmoid_fast(float x) {
    return __builtin_amdgcn_rcpf(1.0f + __expf(-x));
}

__global__ __launch_bounds__(BLOCK, 4) void attn_pool_kernel(
    const float* __restrict__ queries, const float* __restrict__ keys,
    const int* __restrict__ masks, const float* __restrict__ W1,
    const float* __restrict__ b1, const float* __restrict__ W2,
    const float* __restrict__ b2, const float* __restrict__ W3,
    const float* __restrict__ b3, float* __restrict__ out)
{
    __shared__ __align__(16) u16   lds_kh[TT][KSH];    // 27,200 B  K bf16
    __shared__ __align__(16) u16   lds_cwt[16][CWS];   // 4,224 B   cols 0..63 CW (q-dep), 64..127 AC
    __shared__ __align__(16) u16   lds_q16[DD];        // 128 B
    __shared__ __align__(16) u16   lds_s[TT][8];       // 3,200 B   scores bf16
    __shared__ __align__(16) float lds_w[52];          // 208 B     0..31 W2, 32..35 W3, 36..39 b2, 40..47 b1, 48 b3
    __shared__ __align__(16) float lds_e[TT];          // 800 B
    __shared__ __align__(16) float red[4];             // 16 B      => 35,776 B -> 4 blocks/CU
    float* part = (float*)&lds_s[0][0];                // [4][64] f32 alias (s dead after tail)

    const int b = blockIdx.x;
    const int tid = threadIdx.x;
    const int wave = tid >> 6;
    const int lane = tid & 63;

    // ---- masks first (2 tiny loads) ----
    int m0 = 0, m1 = 0;
    if (tid < 100) {
        m0 = masks[(size_t)b * TT + tid];
        m1 = masks[(size_t)b * TT + tid + 100];
    }

    // ---- stage K: fp32 global -> bf16 LDS (keys read exactly once; proven R5 loop) ----
    const float4* kp = (const float4*)(keys + (size_t)b * TT * DD);
#pragma unroll
    for (int k = 0; k < 13; ++k) {
        int i = tid + (k << 8);
        if (i < TT * DD / 4) {
            float4 v = kp[i];
            u32 r0 = cvt_pk_bf16(v.x, v.y);
            u32 r1 = cvt_pk_bf16(v.z, v.w);
            int row = i >> 4, col = (i & 15) << 2;
            uint2 wpack; wpack.x = r0; wpack.y = r1;
            *(uint2*)&lds_kh[row][col] = wpack;
        }
    }

    // ---- weight folds (overlap the staging stream) ----
    const int d_f = tid & 63;
    const int jr = tid >> 6;            // this thread folds rows (jr, jr+4) at col d_f
    {
        const float w1c0 = W1[(128 + d_f) * 8 + jr];
        const float wbc0 = W1[(64 + d_f) * 8 + jr] - w1c0;
        const float wd0  = W1[(192 + d_f) * 8 + jr];
        const float wac0 = W1[d_f * 8 + jr] + w1c0;
        const float w1c1 = W1[(128 + d_f) * 8 + jr + 4];
        const float wbc1 = W1[(64 + d_f) * 8 + jr + 4] - w1c1;
        const float wd1  = W1[(192 + d_f) * 8 + jr + 4];
        const float wac1 = W1[d_f * 8 + jr + 4] + w1c1;
        const float qd = queries[(size_t)b * DD + d_f];
        lds_cwt[jr][64 + d_f]     = f2bf(wac0);
        lds_cwt[jr + 4][64 + d_f] = f2bf(wac1);
        lds_cwt[jr][d_f]          = f2bf(fmaf(qd, wd0, wbc0));
        lds_cwt[jr + 4][d_f]      = f2bf(fmaf(qd, wd1, wbc1));
        if (tid < DD) lds_q16[tid] = f2bf(qd);
    }
    if (tid < 32)       lds_w[tid] = W2[tid];
    else if (tid < 36)  lds_w[tid] = W3[tid - 32];
    else if (tid < 40)  lds_w[tid] = b2[tid - 36];
    else if (tid < 48)  lds_w[tid] = b1[tid - 40];
    else if (tid == 48) lds_w[48]  = b3[0];
    __syncthreads();   // B1: kh, cwt, q16, w ready

    // ---- score GEMM (K=128): S = [K | q] @ [CW ; AC] -> lds_s bf16 ----
    {
        const int r = lane & 15, g = lane >> 4;
        Frag bf0, bf1, bq0, bq1, aq0, aq1;
        bf0.h[0] = *(const uint2*)&lds_cwt[r][g * 8];
        bf0.h[1] = *(const uint2*)&lds_cwt[r][g * 8 + 4];
        bf1.h[0] = *(const uint2*)&lds_cwt[r][32 + g * 8];
        bf1.h[1] = *(const uint2*)&lds_cwt[r][32 + g * 8 + 4];
        bq0.h[0] = *(const uint2*)&lds_cwt[r][64 + g * 8];
        bq0.h[1] = *(const uint2*)&lds_cwt[r][64 + g * 8 + 4];
        bq1.h[0] = *(const uint2*)&lds_cwt[r][96 + g * 8];
        bq1.h[1] = *(const uint2*)&lds_cwt[r][96 + g * 8 + 4];
        aq0.h[0] = *(const uint2*)&lds_q16[g * 8];         // row-constant A (q)
        aq0.h[1] = *(const uint2*)&lds_q16[g * 8 + 4];
        aq1.h[0] = *(const uint2*)&lds_q16[32 + g * 8];
        aq1.h[1] = *(const uint2*)&lds_q16[32 + g * 8 + 4];
        f32x4 zero = {0.0f, 0.0f, 0.0f, 0.0f};
        f32x4 acc_base = __builtin_amdgcn_mfma_f32_16x16x32_bf16(aq1.v, bq1.v, zero, 0, 0, 0);
        acc_base = __builtin_amdgcn_mfma_f32_16x16x32_bf16(aq0.v, bq0.v, acc_base, 0, 0, 0);
        for (int tile = wave; tile < NTILE; tile += 4) {
            int t0 = tile << 4;
            if (t0 > TT - 16) t0 = TT - 16;
            Frag a0, a1;
            a0.h[0] = *(const uint2*)&lds_kh[t0 + r][g * 8];
            a0.h[1] = *(const uint2*)&lds_kh[t0 + r][g * 8 + 4];
            a1.h[0] = *(const uint2*)&lds_kh[t0 + r][32 + g * 8];
            a1.h[1] = *(const uint2*)&lds_kh[t0 + r][32 + g * 8 + 4];
            f32x4 acc = __builtin_amdgcn_mfma_f32_16x16x32_bf16(a0.v, bf0.v, acc_base, 0, 0, 0);
            acc = __builtin_amdgcn_mfma_f32_16x16x32_bf16(a1.v, bf1.v, acc, 0, 0, 0);
            if (r < 8) {                 // D: col(j)=lane&15, row(t)=g*4+reg
                const int rr = t0 + (g << 2);
                lds_s[rr + 0][r] = f2bf(acc[0]);
                lds_s[rr + 1][r] = f2bf(acc[1]);
                lds_s[rr + 2][r] = f2bf(acc[2]);
                lds_s[rr + 3][r] = f2bf(acc[3]);
            }
        }
    }
    __syncthreads();   // B2: S ready

    // ---- MLP tail + fused esum: threads 0..99, rows (t, t+100) ----
    float epart = 0.0f;
    if (tid < 100) {
        const int t0 = tid, t1 = tid + 100;
        ushort8 sa8 = *(const ushort8*)&lds_s[t0][0];
        ushort8 sb8 = *(const ushort8*)&lds_s[t1][0];
        float4 b1A = *(const float4*)&lds_w[40];
        float4 b1B = *(const float4*)&lds_w[44];
        float bv[8] = {b1A.x, b1A.y, b1A.z, b1A.w, b1B.x, b1B.y, b1B.z, b1B.w};
        float h1a[8], h1b[8];
#pragma unroll
        for (int j = 0; j < 8; ++j) {
            h1a[j] = sigmoid_fast(bf2f(sa8[j]) + bv[j]);
            h1b[j] = sigmoid_fast(bf2f(sb8[j]) + bv[j]);
        }
        float sa = lds_w[48], sb = lds_w[48];
#pragma unroll
        for (int c = 0; c < 4; ++c) {
            float ha = lds_w[36 + c], hb = ha;
#pragma unroll
            for (int j = 0; j < 8; ++j) {
                float w2 = lds_w[j * 4 + c];
                ha = fmaf(h1a[j], w2, ha);
                hb = fmaf(h1b[j], w2, hb);
            }
            float w3 = lds_w[32 + c];
            sa = fmaf(sigmoid_fast(ha), w3, sa);
            sb = fmaf(sigmoid_fast(hb), w3, sb);
        }
        // no-max softmax: |score| bounded (<~0.5), masked -> exactly 0
        float ea = m0 ? __expf(sa) : 0.0f;
        float eb = m1 ? __expf(sb) : 0.0f;
        lds_e[t0] = ea;
        lds_e[t1] = eb;
        epart = ea + eb;
    }
#pragma unroll
    for (int off = 32; off; off >>= 1) epart += __shfl_xor(epart, off, 64);
    if (lane == 0) red[wave] = epart;
    __syncthreads();   // B3: e + red ready; lds_s dead -> part alias live

    // ---- PV from bf16 kh (2-way-free): lane = (half, d-pair) ----
    {
        const int half = lane >> 5;
        const int dp = lane & 31;
        const int d0 = dp << 1;
        const int tbase = (wave << 1) + half;   // 0..7
        float acc0 = 0.0f, acc1 = 0.0f;
#pragma unroll
        for (int i = 0; i < 25; ++i) {
            const int t = tbase + (i << 3);
            u32 kw = *(const u32*)&lds_kh[t][d0];
            float e = lds_e[t];
            acc0 = fmaf(e, bflo(kw), acc0);
            acc1 = fmaf(e, bfhi(kw), acc1);
        }
        acc0 += __shfl_xor(acc0, 32, 64);
        acc1 += __shfl_xor(acc1, 32, 64);
        if (half == 0) {
            float2 wpack; wpack.x = acc0; wpack.y = acc1;
            *(float2*)&part[wave * DD + d0] = wpack;
        }
    }
    __syncthreads();   // B4: partials ready

    // ---- epilogue (wave 0): combine + store (no reduction work left) ----
    if (wave == 0) {
        float tot = red[0] + red[1] + red[2] + red[3];
        float r = part[lane] + part[DD + lane] + part[2 * DD + lane] + part[3 * DD + lane];
        out[(size_t)b * DD + lane] = r / tot;
    }
}

extern "C" void kernel_launch(void* const* d_in, const int* in_sizes, int n_in,
                              void* d_out, int out_size, void* d_ws, size_t ws_size,
                              hipStream_t stream) {
    const float* queries = (const float*)d_in[0];
    const float* keys    = (const float*)d_in[1];
    const int*   masks   = (const int*)d_in[2];
    const float* W1      = (const float*)d_in[3];
    const float* b1      = (const float*)d_in[4];
    const float* W2      = (const float*)d_in[5];
    const float* b2      = (const float*)d_in[6];
    const float* W3      = (const float*)d_in[7];
    const float* b3      = (const float*)d_in[8];
    float* out = (float*)d_out;

    const int B = in_sizes[0] / DD;  // 4096
    attn_pool_kernel<<<B, BLOCK, 0, stream>>>(queries, keys, masks, W1, b1, W2, b2, W3, b3, out);
}

// Round 11
// 38.688 us; speedup vs baseline: 2.2790x; 1.4389x over previous
//
#include <hip/hip_runtime.h>

#define TT 200
#define DD 64
#define BLOCK 256
#define KSH 68      // bf16 halfs per kh row: word-stride 34 = 2 mod 32 -> 2-way-free frag reads
#define CWS 132     // bf16 halfs per cwt row: word-stride 66 = 2 mod 32 -> 2-way-free

typedef unsigned short u16;
typedef unsigned int u32;
typedef __attribute__((ext_vector_type(8))) short short8v;  // MFMA bf16x8 frag
typedef __attribute__((ext_vector_type(4))) float f32x4;    // MFMA acc

union Frag { uint2 h[2]; short8v v; };

__device__ __forceinline__ float bflo(u32 w) {
    union { u32 u; float f; } v; v.u = w << 16; return v.f;
}
__device__ __forceinline__ float bfhi(u32 w) {
    union { u32 u; float f; } v; v.u = w & 0xFFFF0000u; return v.f;
}
__device__ __forceinline__ u16 f2bf(float f) {
    union { float f; u32 u; } v; v.f = f;
    return (u16)((v.u + 0x7FFFu + ((v.u >> 16) & 1u)) >> 16);
}
__device__ __forceinline__ u32 cvt_pk_bf16(float lo, float hi) {
    u32 r;
    asm("v_cvt_pk_bf16_f32 %0, %1, %2" : "=v"(r) : "v"(lo), "v"(hi));
    return r;
}
__device__ __forceinline__ float sigmoid_fast(float x) {
    return __builtin_amdgcn_rcpf(1.0f + __expf(-x));
}

// LDS-only barrier: drain LDS ops, sync, fence scheduler. NO vmcnt drain:
// in-flight chunk loads cross it (R8/R9-validated for correctness).
#define BARRIER() do {                                              \
    asm volatile("s_waitcnt lgkmcnt(0)" ::: "memory");              \
    __builtin_amdgcn_sched_barrier(0);                              \
    __builtin_amdgcn_s_barrier();                                   \
    __builtin_amdgcn_sched_barrier(0);                              \
} while (0)

__global__ __launch_bounds__(BLOCK, 4) void attn_pool_kernel(
    const float* __restrict__ queries, const float* __restrict__ keys,
    const int* __restrict__ masks, const float* __restrict__ W1,
    const float* __restrict__ b1, const float* __restrict__ W2,
    const float* __restrict__ b2, const float* __restrict__ W3,
    const float* __restrict__ b3, float* __restrict__ out)
{
    __shared__ __align__(16) u16   lds_kh[TT][KSH];    // 27,200 B
    __shared__ __align__(16) u16   lds_cwt[16][CWS];   // 4,224 B  cols 0..63 CW (q-dep), 64..127 AC
    __shared__ __align__(16) u16   lds_q16[DD];        // 128 B
    __shared__ __align__(16) float lds_s[TT][8];       // 6,400 B  scores fp32
    __shared__ __align__(16) float lds_w[52];          // 208 B
    __shared__ __align__(16) float lds_e[TT];          // 800 B
    __shared__ __align__(16) float red[4];             // 16 B   => ~38.9 KB -> 4 blocks/CU
    float* part = (float*)&lds_s[0][0];                // [4][64] f32 alias (s dead after tail)

    const int b = blockIdx.x;
    const int tid = threadIdx.x;
    const int wave = tid >> 6;
    const int lane = tid & 63;

    // ======== P: issue K chunks 0,1 FIRST (oldest in vmcnt FIFO) ========
    const float4* kp = (const float4*)(keys + (size_t)b * TT * DD);
    float4 L0[4], L1[4], L2[4], L3;
#pragma unroll
    for (int j = 0; j < 4; ++j) L0[j] = kp[(j << 8) + tid];          // rows 0..63
#pragma unroll
    for (int j = 0; j < 4; ++j) L1[j] = kp[1024 + (j << 8) + tid];   // rows 64..127
    __builtin_amdgcn_sched_barrier(0);

    // ---- batch-scalar loads (younger than L0/L1; waited only later) ----
    int m0 = 0, m1 = 0;
    if (tid < 100) {
        m0 = masks[(size_t)b * TT + tid];
        m1 = masks[(size_t)b * TT + tid + 100];
    }
    const int d_f = tid & 63;
    const int jr = tid >> 6;
    const float w1c0 = W1[(128 + d_f) * 8 + jr];
    const float wbc0 = W1[(64 + d_f) * 8 + jr] - w1c0;
    const float wd0  = W1[(192 + d_f) * 8 + jr];
    const float wac0 = W1[d_f * 8 + jr] + w1c0;
    const float w1c1 = W1[(128 + d_f) * 8 + jr + 4];
    const float wbc1 = W1[(64 + d_f) * 8 + jr + 4] - w1c1;
    const float wd1  = W1[(192 + d_f) * 8 + jr + 4];
    const float wac1 = W1[d_f * 8 + jr + 4] + w1c1;
    const float qd   = queries[(size_t)b * DD + d_f];
    float wv = 0.0f;
    if (tid < 32)       wv = W2[tid];
    else if (tid < 36)  wv = W3[tid - 32];
    else if (tid < 40)  wv = b2[tid - 36];
    else if (tid < 48)  wv = b1[tid - 40];
    else if (tid == 48) wv = b3[0];
    __builtin_amdgcn_sched_barrier(0);

    // ---- stage c0 (waits L0 only; everything younger stays in flight) ----
#pragma unroll
    for (int j = 0; j < 4; ++j) {
        int idx = (j << 8) + tid;
        float4 v = L0[j];
        uint2 wp; wp.x = cvt_pk_bf16(v.x, v.y); wp.y = cvt_pk_bf16(v.z, v.w);
        *(uint2*)&lds_kh[idx >> 4][(idx & 15) << 2] = wp;
    }
    // ---- issue chunks 2,3 ----
#pragma unroll
    for (int j = 0; j < 4; ++j) L2[j] = kp[2048 + (j << 8) + tid];   // rows 128..191
    L3 = kp[3072 + (tid & 127)];                                     // rows 192..199 (dup for tid>=128)
    __builtin_amdgcn_sched_barrier(0);

    // ---- folds (wait W1/q; L2/L3 are younger -> remain in flight) ----
    lds_cwt[jr][64 + d_f]     = f2bf(wac0);
    lds_cwt[jr + 4][64 + d_f] = f2bf(wac1);
    lds_cwt[jr][d_f]          = f2bf(fmaf(qd, wd0, wbc0));
    lds_cwt[jr + 4][d_f]      = f2bf(fmaf(qd, wd1, wbc1));
    if (tid < DD) lds_q16[tid] = f2bf(qd);
    if (tid < 49) lds_w[tid] = wv;
    BARRIER();   // B1: c0 rows + cwt + q16 + w ready

    // ======== pipelined GEMM: compute chunk k || stage chunk k+1 ========
    const int r = lane & 15, g = lane >> 4;
    Frag bf0, bf1, bq0, bq1, aq0, aq1;
    bf0.h[0] = *(const uint2*)&lds_cwt[r][g * 8];
    bf0.h[1] = *(const uint2*)&lds_cwt[r][g * 8 + 4];
    bf1.h[0] = *(const uint2*)&lds_cwt[r][32 + g * 8];
    bf1.h[1] = *(const uint2*)&lds_cwt[r][32 + g * 8 + 4];
    bq0.h[0] = *(const uint2*)&lds_cwt[r][64 + g * 8];
    bq0.h[1] = *(const uint2*)&lds_cwt[r][64 + g * 8 + 4];
    bq1.h[0] = *(const uint2*)&lds_cwt[r][96 + g * 8];
    bq1.h[1] = *(const uint2*)&lds_cwt[r][96 + g * 8 + 4];
    aq0.h[0] = *(const uint2*)&lds_q16[g * 8];
    aq0.h[1] = *(const uint2*)&lds_q16[g * 8 + 4];
    aq1.h[0] = *(const uint2*)&lds_q16[32 + g * 8];
    aq1.h[1] = *(const uint2*)&lds_q16[32 + g * 8 + 4];
    f32x4 zero = {0.0f, 0.0f, 0.0f, 0.0f};
    f32x4 acc_base = __builtin_amdgcn_mfma_f32_16x16x32_bf16(aq1.v, bq1.v, zero, 0, 0, 0);
    acc_base = __builtin_amdgcn_mfma_f32_16x16x32_bf16(aq0.v, bq0.v, acc_base, 0, 0, 0);

    auto gemm_tile = [&](int t0) {
        Frag a0, a1;
        a0.h[0] = *(const uint2*)&lds_kh[t0 + r][g * 8];
        a0.h[1] = *(const uint2*)&lds_kh[t0 + r][g * 8 + 4];
        a1.h[0] = *(const uint2*)&lds_kh[t0 + r][32 + g * 8];
        a1.h[1] = *(const uint2*)&lds_kh[t0 + r][32 + g * 8 + 4];
        f32x4 acc = __builtin_amdgcn_mfma_f32_16x16x32_bf16(a0.v, bf0.v, acc_base, 0, 0, 0);
        acc = __builtin_amdgcn_mfma_f32_16x16x32_bf16(a1.v, bf1.v, acc, 0, 0, 0);
        if (r < 8) {                 // D: col(j)=lane&15, row(t)=g*4+reg
            const int rr = t0 + (g << 2);
            lds_s[rr + 0][r] = acc[0];
            lds_s[rr + 1][r] = acc[1];
            lds_s[rr + 2][r] = acc[2];
            lds_s[rr + 3][r] = acc[3];
        }
    };
    auto stage4 = [&](const float4* Lv, int base) {
#pragma unroll
        for (int j = 0; j < 4; ++j) {
            int idx = base + (j << 8) + tid;
            float4 v = Lv[j];
            uint2 wp; wp.x = cvt_pk_bf16(v.x, v.y); wp.y = cvt_pk_bf16(v.z, v.w);
            *(uint2*)&lds_kh[idx >> 4][(idx & 15) << 2] = wp;
        }
    };

    // R0: tiles 0-3 (rows 0-63) || stage c1 (rows 64-127)
    gemm_tile(wave << 4);
    stage4(L1, 1024);
    BARRIER();
    // R1: tiles 4-7 || stage c2 (rows 128-191)
    gemm_tile((4 + wave) << 4);
    stage4(L2, 2048);
    BARRIER();
    // R2: tiles 8-11 || stage c3 (rows 192-199)
    gemm_tile((8 + wave) << 4);
    if (tid < 128) {
        int idx = 3072 + tid;
        float4 v = L3;
        uint2 wp; wp.x = cvt_pk_bf16(v.x, v.y); wp.y = cvt_pk_bf16(v.z, v.w);
        *(uint2*)&lds_kh[idx >> 4][(idx & 15) << 2] = wp;
    }
    BARRIER();
    // R3: clamped last tile (t0=184; rows 184-191 dup-computed, identical values)
    if (wave == 0) gemm_tile(TT - 16);
    BARRIER();   // S complete

    // ---- MLP tail + fused esum: threads 0..99, rows (t, t+100) ----
    float epart = 0.0f;
    if (tid < 100) {
        const int t0 = tid, t1 = tid + 100;
        float4 sa0 = *(const float4*)&lds_s[t0][0];
        float4 sa1 = *(const float4*)&lds_s[t0][4];
        float4 sb0 = *(const float4*)&lds_s[t1][0];
        float4 sb1 = *(const float4*)&lds_s[t1][4];
        float4 b1A = *(const float4*)&lds_w[40];
        float4 b1B = *(const float4*)&lds_w[44];
        float h1a[8], h1b[8];
        h1a[0] = sigmoid_fast(sa0.x + b1A.x); h1b[0] = sigmoid_fast(sb0.x + b1A.x);
        h1a[1] = sigmoid_fast(sa0.y + b1A.y); h1b[1] = sigmoid_fast(sb0.y + b1A.y);
        h1a[2] = sigmoid_fast(sa0.z + b1A.z); h1b[2] = sigmoid_fast(sb0.z + b1A.z);
        h1a[3] = sigmoid_fast(sa0.w + b1A.w); h1b[3] = sigmoid_fast(sb0.w + b1A.w);
        h1a[4] = sigmoid_fast(sa1.x + b1B.x); h1b[4] = sigmoid_fast(sb1.x + b1B.x);
        h1a[5] = sigmoid_fast(sa1.y + b1B.y); h1b[5] = sigmoid_fast(sb1.y + b1B.y);
        h1a[6] = sigmoid_fast(sa1.z + b1B.z); h1b[6] = sigmoid_fast(sb1.z + b1B.z);
        h1a[7] = sigmoid_fast(sa1.w + b1B.w); h1b[7] = sigmoid_fast(sb1.w + b1B.w);
        float sa = lds_w[48], sb = lds_w[48];
#pragma unroll
        for (int c = 0; c < 4; ++c) {
            float ha = lds_w[36 + c], hb = ha;
#pragma unroll
            for (int j = 0; j < 8; ++j) {
                float w2 = lds_w[j * 4 + c];
                ha = fmaf(h1a[j], w2, ha);
                hb = fmaf(h1b[j], w2, hb);
            }
            float w3 = lds_w[32 + c];
            sa = fmaf(sigmoid_fast(ha), w3, sa);
            sb = fmaf(sigmoid_fast(hb), w3, sb);
        }
        float ea = m0 ? __expf(sa) : 0.0f;   // no-max softmax: |score| bounded
        float eb = m1 ? __expf(sb) : 0.0f;
        lds_e[t0] = ea;
        lds_e[t1] = eb;
        epart = ea + eb;
    }
#pragma unroll
    for (int off = 32; off; off >>= 1) epart += __shfl_xor(epart, off, 64);
    if (lane == 0) red[wave] = epart;
    BARRIER();   // B3: e + red ready; lds_s dead -> part alias live

    // ---- PV from bf16 kh (2-way-free): lane = (half, d-pair) ----
    {
        const int half = lane >> 5;
        const int dp = lane & 31;
        const int d0 = dp << 1;
        const int tbase = (wave << 1) + half;   // 0..7
        float acc0 = 0.0f, acc1 = 0.0f;
#pragma unroll
        for (int i = 0; i < 25; ++i) {
            const int t = tbase + (i << 3);
            u32 kw = *(const u32*)&lds_kh[t][d0];
            float e = lds_e[t];
            acc0 = fmaf(e, bflo(kw), acc0);
            acc1 = fmaf(e, bfhi(kw), acc1);
        }
        acc0 += __shfl_xor(acc0, 32, 64);
        acc1 += __shfl_xor(acc1, 32, 64);
        if (half == 0) {
            float2 wpack; wpack.x = acc0; wpack.y = acc1;
            *(float2*)&part[wave * DD + d0] = wpack;
        }
    }
    BARRIER();   // B4: partials ready

    // ---- epilogue (wave 0): combine + store ----
    if (wave == 0) {
        float tot = red[0] + red[1] + red[2] + red[3];
        float rr = part[lane] + part[DD + lane] + part[2 * DD + lane] + part[3 * DD + lane];
        out[(size_t)b * DD + lane] = rr / tot;
    }
}

extern "C" void kernel_launch(void* const* d_in, const int* in_sizes, int n_in,
                              void* d_out, int out_size, void* d_ws, size_t ws_size,
                              hipStream_t stream) {
    const float* queries = (const float*)d_in[0];
    const float* keys    = (const float*)d_in[1];
    const int*   masks   = (const int*)d_in[2];
    const float* W1      = (const float*)d_in[3];
    const float* b1      = (const float*)d_in[4];
    const float* W2      = (const float*)d_in[5];
    const float* b2      = (const float*)d_in[6];
    const float* W3      = (const float*)d_in[7];
    const float* b3      = (const float*)d_in[8];
    float* out = (float*)d_out;

    const int B = in_sizes[0] / DD;  // 4096
    attn_pool_kernel<<<B, BLOCK, 0, stream>>>(queries, keys, masks, W1, b1, W2, b2, W3, b3, out);
}